// Round 1
// baseline (94746.912 us; speedup 1.0000x reference)
//
#include <hip/hip_runtime.h>

#define DEVFN __device__ __forceinline__

// ---------- DPP helper: within-16-lane rotate, dst[l] = src[(l-R)&15] ----------
template<int R>
DEVFN float row_ror(float v) {
    return __int_as_float(__builtin_amdgcn_update_dpp(
        0, __float_as_int(v), 0x120 + R, 0xF, 0xF, true));
}

// tanh(x) = sign(x) * (1 - e^{-2|x|}) / (1 + e^{-2|x|}); exact formula, ~2-3 ulp
DEVFN float fast_tanh(float v) {
    float ax = fabsf(v);
    float t  = __builtin_amdgcn_exp2f(ax * -2.8853900817779268f);  // exp(-2*ax)
    float r  = (1.0f - t) * __builtin_amdgcn_rcpf(1.0f + t);
    return copysignf(r, v);
}

static constexpr int B = 64, U = 4096, H = 64;
static constexpr int N = B * U;  // 262144 sequential steps

// ============================================================================
// Kernel 1: parallel input projection.
// x'[i][j] = sum_k emb[ids[i]][k] * W_ih[j][k] + b_ih[j] + b_hh[j]
// ids[i] = y[i%B][i/B]   (time-major chain order)
// One wave per 64 rows; lane j owns output column j (W_ih row j in registers),
// emb rows staged through LDS and read via broadcast float4.
// ============================================================================
__global__ __launch_bounds__(64) void proj_kernel(
    const int*   __restrict__ y,      // [B][U]
    const float* __restrict__ emb,    // [V][H]
    const float* __restrict__ W_ih,   // [H][H]
    const float* __restrict__ b_ih,
    const float* __restrict__ b_hh,
    float*       __restrict__ xout)   // [N][H]
{
    __shared__ __align__(16) float e_s[64][H];
    __shared__ int ids_s[64];
    const int l    = threadIdx.x;          // 0..63
    const int row0 = blockIdx.x * 64;

    // lane l holds W_ih row l
    float w[H];
    #pragma unroll
    for (int k4 = 0; k4 < 16; ++k4) {
        float4 v = *(const float4*)&W_ih[l * H + k4 * 4];
        w[k4*4+0] = v.x; w[k4*4+1] = v.y; w[k4*4+2] = v.z; w[k4*4+3] = v.w;
    }
    const float bias = b_ih[l] + b_hh[l];

    {   // token id for row (row0 + l):  t = i/B, b = i%B, id = y[b*U + t]
        int i = row0 + l;
        ids_s[l] = y[(i & (B - 1)) * U + (i >> 6)];
    }
    __syncthreads();

    // stage 64 embedding rows: iteration r loads row r, lane l loads column l
    #pragma unroll 4
    for (int r = 0; r < 64; ++r) {
        e_s[r][l] = emb[ids_s[r] * H + l];
    }
    __syncthreads();

    #pragma unroll 1
    for (int r = 0; r < 64; ++r) {
        float acc0 = bias, acc1 = 0.f;
        #pragma unroll
        for (int k4 = 0; k4 < 16; ++k4) {
            float4 ev = *(const float4*)&e_s[r][k4 * 4];   // broadcast read
            acc0 = fmaf(ev.x, w[k4*4+0], acc0);
            acc1 = fmaf(ev.y, w[k4*4+1], acc1);
            acc0 = fmaf(ev.z, w[k4*4+2], acc0);
            acc1 = fmaf(ev.w, w[k4*4+3], acc1);
        }
        xout[(row0 + r) * H + l] = acc0 + acc1;  // coalesced 256B store
    }
}

// ============================================================================
// Kernel 2: the sequential scan. ONE wave total (inherent: single recurrence
// chain of length 262144). Lane j owns h[j] and W_hh row j.
//   per step: 4x ds_bpermute build hb_b[l] = h[16b + (l&15)],
//             64 FMAs with DPP row_ror fused on src0 (w pre-permuted to match),
//             tanh, in-place overwrite of x' with h in d_out.
// ============================================================================
__global__ __launch_bounds__(64, 1) void scan_kernel(
    const float* __restrict__ W_hh,   // [H][H]
    const float* __restrict__ h0,     // [H]
    const float* __restrict__ xin,    // [N][H]  (= d_out holding x')
    float*       __restrict__ xout)   // [N][H]  (= d_out, overwritten with h)
{
    const int j = threadIdx.x;        // 0..63

    // w[b*16+r] = W_hh[j][16b + ((j - r) & 15)]  — matches row_ror:r source lane
    float w[64];
    #pragma unroll
    for (int b = 0; b < 4; ++b)
        #pragma unroll
        for (int r = 0; r < 16; ++r)
            w[b * 16 + r] = W_hh[j * H + b * 16 + (((j & 15) - r) & 15)];

    float h = h0[j];

    // bpermute byte indices: lane l pulls h from lane 16b + (l&15)
    const int a0 = ((j & 15) + 0)  * 4;
    const int a1 = ((j & 15) + 16) * 4;
    const int a2 = ((j & 15) + 32) * 4;
    const int a3 = ((j & 15) + 48) * 4;

    constexpr int PF = 8;             // prefetch depth (steps)
    float xf[PF];
    #pragma unroll
    for (int p = 0; p < PF; ++p) xf[p] = xin[p * H + j];

    #pragma unroll 1
    for (int i = 0; i < N; i += PF) {
        #pragma unroll
        for (int p = 0; p < PF; ++p) {
            const int hbits = __float_as_int(h);
            float hb0 = __int_as_float(__builtin_amdgcn_ds_bpermute(a0, hbits));
            float hb1 = __int_as_float(__builtin_amdgcn_ds_bpermute(a1, hbits));
            float hb2 = __int_as_float(__builtin_amdgcn_ds_bpermute(a2, hbits));
            float hb3 = __int_as_float(__builtin_amdgcn_ds_bpermute(a3, hbits));

            float acc0 = xf[p];       // x' already includes both biases
            float acc1 = 0.f, acc2 = 0.f, acc3 = 0.f;

            acc0 = fmaf(hb0, w[0],  acc0);
            acc1 = fmaf(hb1, w[16], acc1);
            acc2 = fmaf(hb2, w[32], acc2);
            acc3 = fmaf(hb3, w[48], acc3);
            #define STEP_R(R)                                   \
                acc0 = fmaf(row_ror<R>(hb0), w[R],      acc0);  \
                acc1 = fmaf(row_ror<R>(hb1), w[16 + R], acc1);  \
                acc2 = fmaf(row_ror<R>(hb2), w[32 + R], acc2);  \
                acc3 = fmaf(row_ror<R>(hb3), w[48 + R], acc3);
            STEP_R(1)  STEP_R(2)  STEP_R(3)  STEP_R(4)  STEP_R(5)
            STEP_R(6)  STEP_R(7)  STEP_R(8)  STEP_R(9)  STEP_R(10)
            STEP_R(11) STEP_R(12) STEP_R(13) STEP_R(14) STEP_R(15)
            #undef STEP_R

            h = fast_tanh((acc0 + acc1) + (acc2 + acc3));

            xout[(i + p) * H + j] = h;          // fire-and-forget, coalesced

            const int nf = i + p + PF;          // refill prefetch ring
            if (nf < N) xf[p] = xin[nf * H + j];
        }
    }
}

// ============================================================================
extern "C" void kernel_launch(void* const* d_in, const int* in_sizes, int n_in,
                              void* d_out, int out_size, void* d_ws, size_t ws_size,
                              hipStream_t stream) {
    const int*   y    = (const int*)  d_in[0];
    const float* emb  = (const float*)d_in[1];
    const float* W_ih = (const float*)d_in[2];
    const float* W_hh = (const float*)d_in[3];
    const float* b_ih = (const float*)d_in[4];
    const float* b_hh = (const float*)d_in[5];
    const float* h0   = (const float*)d_in[6];
    float* out = (float*)d_out;

    // Stage x' directly in d_out; scan overwrites it in place (strict
    // read-before-write per element within the single sequential wave).
    proj_kernel<<<dim3(N / 64), dim3(64), 0, stream>>>(y, emb, W_ih, b_ih, b_hh, out);
    scan_kernel<<<dim3(1), dim3(64), 0, stream>>>(W_hh, h0, out, out);
}

// Round 2
// 63969.537 us; speedup vs baseline: 1.4811x; 1.4811x over previous
//
#include <hip/hip_runtime.h>

#define DEVFN __device__ __forceinline__

// ---------- DPP helper: within-16-lane rotate, dst[l] = src[(l-R)&15] ----------
template<int R>
DEVFN float row_ror(float v) {
    return __int_as_float(__builtin_amdgcn_update_dpp(
        0, __float_as_int(v), 0x120 + R, 0xF, 0xF, true));
}

// tanh(x) = sign(x) * (1 - e^{-2|x|}) / (1 + e^{-2|x|}); exact formula, ~2-3 ulp
DEVFN float fast_tanh(float v) {
    float ax = fabsf(v);
    float t  = __builtin_amdgcn_exp2f(ax * -2.8853900817779268f);  // exp(-2*ax)
    float r  = (1.0f - t) * __builtin_amdgcn_rcpf(1.0f + t);
    return copysignf(r, v);
}

static constexpr int B = 64, U = 4096, H = 64;
static constexpr int N = B * U;  // 262144 sequential steps

// ============================================================================
// Kernel 1: parallel input projection (unchanged from R1 — ~noise at 94 ms).
// x'[i][j] = sum_k emb[ids[i]][k] * W_ih[j][k] + b_ih[j] + b_hh[j]
// ============================================================================
__global__ __launch_bounds__(64) void proj_kernel(
    const int*   __restrict__ y,      // [B][U]
    const float* __restrict__ emb,    // [V][H]
    const float* __restrict__ W_ih,   // [H][H]
    const float* __restrict__ b_ih,
    const float* __restrict__ b_hh,
    float*       __restrict__ xout)   // [N][H]
{
    __shared__ __align__(16) float e_s[64][H];
    __shared__ int ids_s[64];
    const int l    = threadIdx.x;          // 0..63
    const int row0 = blockIdx.x * 64;

    float w[H];
    #pragma unroll
    for (int k4 = 0; k4 < 16; ++k4) {
        float4 v = *(const float4*)&W_ih[l * H + k4 * 4];
        w[k4*4+0] = v.x; w[k4*4+1] = v.y; w[k4*4+2] = v.z; w[k4*4+3] = v.w;
    }
    const float bias = b_ih[l] + b_hh[l];

    {
        int i = row0 + l;
        ids_s[l] = y[(i & (B - 1)) * U + (i >> 6)];
    }
    __syncthreads();

    #pragma unroll 4
    for (int r = 0; r < 64; ++r) {
        e_s[r][l] = emb[ids_s[r] * H + l];
    }
    __syncthreads();

    #pragma unroll 1
    for (int r = 0; r < 64; ++r) {
        float acc0 = bias, acc1 = 0.f;
        #pragma unroll
        for (int k4 = 0; k4 < 16; ++k4) {
            float4 ev = *(const float4*)&e_s[r][k4 * 4];
            acc0 = fmaf(ev.x, w[k4*4+0], acc0);
            acc1 = fmaf(ev.y, w[k4*4+1], acc1);
            acc0 = fmaf(ev.z, w[k4*4+2], acc0);
            acc1 = fmaf(ev.w, w[k4*4+3], acc1);
        }
        xout[(row0 + r) * H + l] = acc0 + acc1;
    }
}

// ============================================================================
// Kernel 2: the sequential scan, one wave. R2 change: ALL per-lane state is
// named scalars (no arrays -> no alloca -> no scratch). R1's VGPR_Count=48
// proved w[64]/xf[8] lived in scratch (~64 buffer_loads/step on the critical
// path -> 868 cyc/step).
// ============================================================================

// ---- 64 named weights: wB_R = W_hh[j][16*B + ((j - R) & 15)] ----
#define DW(Bk, R) float w##Bk##_##R = W_hh[j * H + (Bk) * 16 + (((j & 15) - (R)) & 15)];
#define DWBLK(Bk) DW(Bk,0) DW(Bk,1) DW(Bk,2) DW(Bk,3) DW(Bk,4) DW(Bk,5) DW(Bk,6) DW(Bk,7) \
                  DW(Bk,8) DW(Bk,9) DW(Bk,10) DW(Bk,11) DW(Bk,12) DW(Bk,13) DW(Bk,14) DW(Bk,15)

// ---- one rotation step: 4 DPP-fused fmacs ----
#define FR(R)                                              \
    acc0 = fmaf(row_ror<R>(hb0), w0_##R, acc0);            \
    acc1 = fmaf(row_ror<R>(hb1), w1_##R, acc1);            \
    acc2 = fmaf(row_ror<R>(hb2), w2_##R, acc2);            \
    acc3 = fmaf(row_ror<R>(hb3), w3_##R, acc3);

// ---- one recurrence step; XF is a named register, PFETCH is a statement ----
#define SLOT(XF, IDX, PFETCH) {                                              \
    const int hbits = __float_as_int(h);                                     \
    float hb0 = __int_as_float(__builtin_amdgcn_ds_bpermute(a0, hbits));     \
    float hb1 = __int_as_float(__builtin_amdgcn_ds_bpermute(a1, hbits));     \
    float hb2 = __int_as_float(__builtin_amdgcn_ds_bpermute(a2, hbits));     \
    float hb3 = __int_as_float(__builtin_amdgcn_ds_bpermute(a3, hbits));     \
    float acc0 = XF, acc1 = 0.f, acc2 = 0.f, acc3 = 0.f;                     \
    acc0 = fmaf(hb0, w0_0, acc0);                                            \
    acc1 = fmaf(hb1, w1_0, acc1);                                            \
    acc2 = fmaf(hb2, w2_0, acc2);                                            \
    acc3 = fmaf(hb3, w3_0, acc3);                                            \
    FR(1)  FR(2)  FR(3)  FR(4)  FR(5)  FR(6)  FR(7)                          \
    FR(8)  FR(9)  FR(10) FR(11) FR(12) FR(13) FR(14) FR(15)                  \
    h = fast_tanh((acc0 + acc1) + (acc2 + acc3));                            \
    op[(IDX) * H] = h;                                                       \
    PFETCH                                                                   \
}

__global__ __launch_bounds__(64, 1) void scan_kernel(
    const float* __restrict__ W_hh,   // [H][H]
    const float* __restrict__ h0,     // [H]
    const float* __restrict__ xin,    // [N][H]  (= d_out holding x')
    float*       __restrict__ xout)   // [N][H]  (= d_out, overwritten with h)
{
    const int j = threadIdx.x;        // 0..63

    DWBLK(0) DWBLK(1) DWBLK(2) DWBLK(3)   // 64 scalar weights -> VGPRs

    float h = h0[j];

    // bpermute byte indices: lane l pulls h from lane 16b + (l&15)
    const int a0 = ((j & 15) + 0)  * 4;
    const int a1 = ((j & 15) + 16) * 4;
    const int a2 = ((j & 15) + 32) * 4;
    const int a3 = ((j & 15) + 48) * 4;

    const float* xp = xin  + j;       // lane j's element of row 0
    float*       op = xout + j;

    // 8-deep named prefetch ring: rows 0..7
    float x0 = xp[0*H], x1 = xp[1*H], x2 = xp[2*H], x3 = xp[3*H];
    float x4 = xp[4*H], x5 = xp[5*H], x6 = xp[6*H], x7 = xp[7*H];
    xp += 8 * H;                      // xp now points at row i+8

    #pragma unroll 1
    for (int i = 0; i < N - 8; i += 8) {
        SLOT(x0, 0, x0 = xp[0*H];)
        SLOT(x1, 1, x1 = xp[1*H];)
        SLOT(x2, 2, x2 = xp[2*H];)
        SLOT(x3, 3, x3 = xp[3*H];)
        SLOT(x4, 4, x4 = xp[4*H];)
        SLOT(x5, 5, x5 = xp[5*H];)
        SLOT(x6, 6, x6 = xp[6*H];)
        SLOT(x7, 7, x7 = xp[7*H];)
        xp += 8 * H;
        op += 8 * H;
    }
    // epilogue: last 8 rows, no prefetch
    SLOT(x0, 0, ) SLOT(x1, 1, ) SLOT(x2, 2, ) SLOT(x3, 3, )
    SLOT(x4, 4, ) SLOT(x5, 5, ) SLOT(x6, 6, ) SLOT(x7, 7, )
}

// ============================================================================
extern "C" void kernel_launch(void* const* d_in, const int* in_sizes, int n_in,
                              void* d_out, int out_size, void* d_ws, size_t ws_size,
                              hipStream_t stream) {
    const int*   y    = (const int*)  d_in[0];
    const float* emb  = (const float*)d_in[1];
    const float* W_ih = (const float*)d_in[2];
    const float* W_hh = (const float*)d_in[3];
    const float* b_ih = (const float*)d_in[4];
    const float* b_hh = (const float*)d_in[5];
    const float* h0   = (const float*)d_in[6];
    float* out = (float*)d_out;

    // Stage x' directly in d_out; scan overwrites it in place (strict
    // read-before-write per element within the single sequential wave).
    proj_kernel<<<dim3(N / 64), dim3(64), 0, stream>>>(y, emb, W_ih, b_ih, b_hh, out);
    scan_kernel<<<dim3(1), dim3(64), 0, stream>>>(W_hh, h0, out, out);
}

// Round 4
// 63887.872 us; speedup vs baseline: 1.4830x; 1.0013x over previous
//
#include <hip/hip_runtime.h>

#define DEVFN __device__ __forceinline__

// ---------- DPP helper: within-16-lane rotate, dst[l] = src[(l-R)&15] ----------
template<int R>
DEVFN float row_ror(float v) {
    return __int_as_float(__builtin_amdgcn_update_dpp(
        0, __float_as_int(v), 0x120 + R, 0xF, 0xF, true));
}

// tanh(x) = sign(x) * (1 - e^{-2|x|}) / (1 + e^{-2|x|}); exact formula, ~2-3 ulp
DEVFN float fast_tanh(float v) {
    float ax = fabsf(v);
    float t  = __builtin_amdgcn_exp2f(ax * -2.8853900817779268f);  // exp(-2*ax)
    float r  = (1.0f - t) * __builtin_amdgcn_rcpf(1.0f + t);
    return copysignf(r, v);
}

static constexpr int B = 64, U = 4096, H = 64;
static constexpr int N = B * U;  // 262144 sequential steps

// permlane swap builtins return: unsigned int vector of 2 (index with [0]/[1])
typedef unsigned int v2u __attribute__((__vector_size__(2 * sizeof(unsigned int))));

// ============================================================================
// Kernel 1: parallel input projection (unchanged — noise at this scale).
// x'[i][j] = sum_k emb[ids[i]][k] * W_ih[j][k] + b_ih[j] + b_hh[j]
// ============================================================================
__global__ __launch_bounds__(64) void proj_kernel(
    const int*   __restrict__ y,      // [B][U]
    const float* __restrict__ emb,    // [V][H]
    const float* __restrict__ W_ih,   // [H][H]
    const float* __restrict__ b_ih,
    const float* __restrict__ b_hh,
    float*       __restrict__ xout)   // [N][H]
{
    __shared__ __align__(16) float e_s[64][H];
    __shared__ int ids_s[64];
    const int l    = threadIdx.x;          // 0..63
    const int row0 = blockIdx.x * 64;

    float w[H];
    #pragma unroll
    for (int k4 = 0; k4 < 16; ++k4) {
        float4 v = *(const float4*)&W_ih[l * H + k4 * 4];
        w[k4*4+0] = v.x; w[k4*4+1] = v.y; w[k4*4+2] = v.z; w[k4*4+3] = v.w;
    }
    const float bias = b_ih[l] + b_hh[l];

    {
        int i = row0 + l;
        ids_s[l] = y[(i & (B - 1)) * U + (i >> 6)];
    }
    __syncthreads();

    #pragma unroll 4
    for (int r = 0; r < 64; ++r) {
        e_s[r][l] = emb[ids_s[r] * H + l];
    }
    __syncthreads();

    #pragma unroll 1
    for (int r = 0; r < 64; ++r) {
        float acc0 = bias, acc1 = 0.f;
        #pragma unroll
        for (int k4 = 0; k4 < 16; ++k4) {
            float4 ev = *(const float4*)&e_s[r][k4 * 4];
            acc0 = fmaf(ev.x, w[k4*4+0], acc0);
            acc1 = fmaf(ev.y, w[k4*4+1], acc1);
            acc0 = fmaf(ev.z, w[k4*4+2], acc0);
            acc1 = fmaf(ev.w, w[k4*4+3], acc1);
        }
        xout[(row0 + r) * H + l] = acc0 + acc1;
    }
}

// ============================================================================
// Kernel 2: sequential scan, one wave. R4 = R3 with the permlane accessor
// fixed (builtin returns v2u, indexed [0]/[1]).
// Broadcast h -> 4 block-replicated regs via VALU permlane swaps:
//   p  = swap32(h,h):  p[0] = rows{0,1,0,1}, p[1] = rows{2,3,2,3}  (rows of 16)
//   q0 = swap16(p[0],p[0]): hb0 = [row0 x4], hb1 = [row1 x4]
//   q1 = swap16(p[1],p[1]): hb2 = [row2 x4], hb3 = [row3 x4]
// Then 16 DPP row_ror steps x 4 blocks of fused fmacs (weights pre-permuted).
// ============================================================================

// ---- 64 named weights: wB_R = W_hh[j][16*B + ((j - R) & 15)] ----
#define DW(Bk, R) float w##Bk##_##R = W_hh[j * H + (Bk) * 16 + (((j & 15) - (R)) & 15)];
#define DWBLK(Bk) DW(Bk,0) DW(Bk,1) DW(Bk,2) DW(Bk,3) DW(Bk,4) DW(Bk,5) DW(Bk,6) DW(Bk,7) \
                  DW(Bk,8) DW(Bk,9) DW(Bk,10) DW(Bk,11) DW(Bk,12) DW(Bk,13) DW(Bk,14) DW(Bk,15)

// ---- broadcast h -> 4 block-replicated registers (VALU-only) ----
#define BCAST(h)                                                                     \
    const unsigned hbits = (unsigned)__float_as_int(h);                              \
    v2u p  = __builtin_amdgcn_permlane32_swap(hbits, hbits, false, false);           \
    v2u q0 = __builtin_amdgcn_permlane16_swap(p[0], p[0], false, false);             \
    v2u q1 = __builtin_amdgcn_permlane16_swap(p[1], p[1], false, false);             \
    float hb0 = __int_as_float((int)q0[0]), hb1 = __int_as_float((int)q0[1]);        \
    float hb2 = __int_as_float((int)q1[0]), hb3 = __int_as_float((int)q1[1]);

// ---- one rotation step: 4 DPP-fused fmacs ----
#define FR(R)                                              \
    acc0 = fmaf(row_ror<R>(hb0), w0_##R, acc0);            \
    acc1 = fmaf(row_ror<R>(hb1), w1_##R, acc1);            \
    acc2 = fmaf(row_ror<R>(hb2), w2_##R, acc2);            \
    acc3 = fmaf(row_ror<R>(hb3), w3_##R, acc3);

// ---- one recurrence step; XF is a named register, PFETCH is a statement ----
#define SLOT(XF, IDX, PFETCH) {                                              \
    BCAST(h)                                                                 \
    float acc0 = XF, acc1 = 0.f, acc2 = 0.f, acc3 = 0.f;                     \
    acc0 = fmaf(hb0, w0_0, acc0);                                            \
    acc1 = fmaf(hb1, w1_0, acc1);                                            \
    acc2 = fmaf(hb2, w2_0, acc2);                                            \
    acc3 = fmaf(hb3, w3_0, acc3);                                            \
    FR(1)  FR(2)  FR(3)  FR(4)  FR(5)  FR(6)  FR(7)                          \
    FR(8)  FR(9)  FR(10) FR(11) FR(12) FR(13) FR(14) FR(15)                  \
    h = fast_tanh((acc0 + acc1) + (acc2 + acc3));                            \
    op[(IDX) * H] = h;                                                       \
    PFETCH                                                                   \
}

__global__ __launch_bounds__(64, 1) void scan_kernel(
    const float* __restrict__ W_hh,   // [H][H]
    const float* __restrict__ h0,     // [H]
    const float* __restrict__ xin,    // [N][H]  (= d_out holding x')
    float*       __restrict__ xout)   // [N][H]  (= d_out, overwritten with h)
{
    const int j = threadIdx.x;        // 0..63

    DWBLK(0) DWBLK(1) DWBLK(2) DWBLK(3)   // 64 scalar weights -> VGPRs

    float h = h0[j];

    const float* xp = xin  + j;       // lane j's element of row 0
    float*       op = xout + j;

    // 8-deep named prefetch ring: rows 0..7
    float x0 = xp[0*H], x1 = xp[1*H], x2 = xp[2*H], x3 = xp[3*H];
    float x4 = xp[4*H], x5 = xp[5*H], x6 = xp[6*H], x7 = xp[7*H];
    xp += 8 * H;                      // xp now points at row i+8

    #pragma unroll 1
    for (int i = 0; i < N - 8; i += 8) {
        SLOT(x0, 0, x0 = xp[0*H];)
        SLOT(x1, 1, x1 = xp[1*H];)
        SLOT(x2, 2, x2 = xp[2*H];)
        SLOT(x3, 3, x3 = xp[3*H];)
        SLOT(x4, 4, x4 = xp[4*H];)
        SLOT(x5, 5, x5 = xp[5*H];)
        SLOT(x6, 6, x6 = xp[6*H];)
        SLOT(x7, 7, x7 = xp[7*H];)
        xp += 8 * H;
        op += 8 * H;
    }
    // epilogue: last 8 rows, no prefetch
    SLOT(x0, 0, ) SLOT(x1, 1, ) SLOT(x2, 2, ) SLOT(x3, 3, )
    SLOT(x4, 4, ) SLOT(x5, 5, ) SLOT(x6, 6, ) SLOT(x7, 7, )
}

// ============================================================================
extern "C" void kernel_launch(void* const* d_in, const int* in_sizes, int n_in,
                              void* d_out, int out_size, void* d_ws, size_t ws_size,
                              hipStream_t stream) {
    const int*   y    = (const int*)  d_in[0];
    const float* emb  = (const float*)d_in[1];
    const float* W_ih = (const float*)d_in[2];
    const float* W_hh = (const float*)d_in[3];
    const float* b_ih = (const float*)d_in[4];
    const float* b_hh = (const float*)d_in[5];
    const float* h0   = (const float*)d_in[6];
    float* out = (float*)d_out;

    // Stage x' directly in d_out; scan overwrites it in place (strict
    // read-before-write per element within the single sequential wave).
    proj_kernel<<<dim3(N / 64), dim3(64), 0, stream>>>(y, emb, W_ih, b_ih, b_hh, out);
    scan_kernel<<<dim3(1), dim3(64), 0, stream>>>(W_hh, h0, out, out);
}

// Round 5
// 59268.011 us; speedup vs baseline: 1.5986x; 1.0779x over previous
//
#include <hip/hip_runtime.h>

#define DEVFN __device__ __forceinline__

// tanh(x) = sign(x) * (1 - e^{-2|x|}) / (1 + e^{-2|x|}); exact formula, ~2-3 ulp
DEVFN float fast_tanh(float v) {
    float ax = fabsf(v);
    float t  = __builtin_amdgcn_exp2f(ax * -2.8853900817779268f);  // exp(-2*ax)
    float r  = (1.0f - t) * __builtin_amdgcn_rcpf(1.0f + t);
    return copysignf(r, v);
}

static constexpr int B = 64, U = 4096, H = 64;
static constexpr int N = B * U;  // 262144 sequential steps

// permlane swap builtins return: unsigned int vector of 2 (index with [0]/[1])
typedef unsigned int v2u __attribute__((__vector_size__(2 * sizeof(unsigned int))));

// ============================================================================
// Kernel 1: parallel input projection (unchanged — noise at this scale).
// x'[i][j] = sum_k emb[ids[i]][k] * W_ih[j][k] + b_ih[j] + b_hh[j]
// ============================================================================
__global__ __launch_bounds__(64) void proj_kernel(
    const int*   __restrict__ y,      // [B][U]
    const float* __restrict__ emb,    // [V][H]
    const float* __restrict__ W_ih,   // [H][H]
    const float* __restrict__ b_ih,
    const float* __restrict__ b_hh,
    float*       __restrict__ xout)   // [N][H]
{
    __shared__ __align__(16) float e_s[64][H];
    __shared__ int ids_s[64];
    const int l    = threadIdx.x;          // 0..63
    const int row0 = blockIdx.x * 64;

    float w[H];
    #pragma unroll
    for (int k4 = 0; k4 < 16; ++k4) {
        float4 v = *(const float4*)&W_ih[l * H + k4 * 4];
        w[k4*4+0] = v.x; w[k4*4+1] = v.y; w[k4*4+2] = v.z; w[k4*4+3] = v.w;
    }
    const float bias = b_ih[l] + b_hh[l];

    {
        int i = row0 + l;
        ids_s[l] = y[(i & (B - 1)) * U + (i >> 6)];
    }
    __syncthreads();

    #pragma unroll 4
    for (int r = 0; r < 64; ++r) {
        e_s[r][l] = emb[ids_s[r] * H + l];
    }
    __syncthreads();

    #pragma unroll 1
    for (int r = 0; r < 64; ++r) {
        float acc0 = bias, acc1 = 0.f;
        #pragma unroll
        for (int k4 = 0; k4 < 16; ++k4) {
            float4 ev = *(const float4*)&e_s[r][k4 * 4];
            acc0 = fmaf(ev.x, w[k4*4+0], acc0);
            acc1 = fmaf(ev.y, w[k4*4+1], acc1);
            acc0 = fmaf(ev.z, w[k4*4+2], acc0);
            acc1 = fmaf(ev.w, w[k4*4+3], acc1);
        }
        xout[(row0 + r) * H + l] = acc0 + acc1;
    }
}

// ============================================================================
// Kernel 2: sequential scan, one wave. R5 change: the 60 rotation MACs are
// forced to single fused v_fmac_f32_dpp instructions via inline asm.
// R4 evidence: broadcast method irrelevant (bperm->permlane neutral at ~560
// nominal cyc/step) => cost was the unfused mov_dpp -> v_fma_f32 pairs with
// the RAW stall fully exposed on a single wave (~8-9 cyc per MAC). Fused:
// 1 VOP2 instr per MAC, 4 interleaved chains cover the fmac latency.
// DPP hazard note: permlane writes hb* ; the 4 plain R=0 fmacs sit between
// those writes and the first DPP read of hb* (>=2 instr spacing required).
// ============================================================================

// ---- 64 named weights: wB_R = W_hh[j][16*B + ((j - R) & 15)] ----
#define DW(Bk, R) float w##Bk##_##R = W_hh[j * H + (Bk) * 16 + (((j & 15) - (R)) & 15)];
#define DWBLK(Bk) DW(Bk,0) DW(Bk,1) DW(Bk,2) DW(Bk,3) DW(Bk,4) DW(Bk,5) DW(Bk,6) DW(Bk,7) \
                  DW(Bk,8) DW(Bk,9) DW(Bk,10) DW(Bk,11) DW(Bk,12) DW(Bk,13) DW(Bk,14) DW(Bk,15)

// ---- broadcast h -> 4 block-replicated registers (VALU-only) ----
#define BCAST(h)                                                                     \
    const unsigned hbits = (unsigned)__float_as_int(h);                              \
    v2u p  = __builtin_amdgcn_permlane32_swap(hbits, hbits, false, false);           \
    v2u q0 = __builtin_amdgcn_permlane16_swap(p[0], p[0], false, false);             \
    v2u q1 = __builtin_amdgcn_permlane16_swap(p[1], p[1], false, false);             \
    float hb0 = __int_as_float((int)q0[0]), hb1 = __int_as_float((int)q0[1]);        \
    float hb2 = __int_as_float((int)q1[0]), hb3 = __int_as_float((int)q1[1]);

// ---- fused DPP MAC: acc += rotate16(hb, R) * w   (dst[l] = src[(l-R)&15]) ----
#define FMAC_DPP(ACC, HB, W, R)                                              \
    asm("v_fmac_f32_dpp %0, %1, %2 row_ror:" #R " row_mask:0xf bank_mask:0xf"\
        : "+v"(ACC) : "v"(HB), "v"(W))

// ---- one rotation step: 4 fused fmacs, chains interleaved ----
#define FR(R)                                  \
    FMAC_DPP(acc0, hb0, w0_##R, R);            \
    FMAC_DPP(acc1, hb1, w1_##R, R);            \
    FMAC_DPP(acc2, hb2, w2_##R, R);            \
    FMAC_DPP(acc3, hb3, w3_##R, R);

// ---- one recurrence step; XF is a named register, PFETCH is a statement ----
#define SLOT(XF, IDX, PFETCH) {                                              \
    BCAST(h)                                                                 \
    float acc0 = XF, acc1 = 0.f, acc2 = 0.f, acc3 = 0.f;                     \
    acc0 = fmaf(hb0, w0_0, acc0);  /* plain MACs: also provide >=2-instr */  \
    acc1 = fmaf(hb1, w1_0, acc1);  /* spacing between permlane writes of */  \
    acc2 = fmaf(hb2, w2_0, acc2);  /* hb* and the first DPP read (hazard) */ \
    acc3 = fmaf(hb3, w3_0, acc3);                                            \
    FR(1)  FR(2)  FR(3)  FR(4)  FR(5)  FR(6)  FR(7)                          \
    FR(8)  FR(9)  FR(10) FR(11) FR(12) FR(13) FR(14) FR(15)                  \
    h = fast_tanh((acc0 + acc1) + (acc2 + acc3));                            \
    op[(IDX) * H] = h;                                                       \
    PFETCH                                                                   \
}

__global__ __launch_bounds__(64, 1) void scan_kernel(
    const float* __restrict__ W_hh,   // [H][H]
    const float* __restrict__ h0,     // [H]
    const float* __restrict__ xin,    // [N][H]  (= d_out holding x')
    float*       __restrict__ xout)   // [N][H]  (= d_out, overwritten with h)
{
    const int j = threadIdx.x;        // 0..63

    DWBLK(0) DWBLK(1) DWBLK(2) DWBLK(3)   // 64 scalar weights -> VGPRs

    float h = h0[j];

    const float* xp = xin  + j;       // lane j's element of row 0
    float*       op = xout + j;

    // 8-deep named prefetch ring: rows 0..7
    float x0 = xp[0*H], x1 = xp[1*H], x2 = xp[2*H], x3 = xp[3*H];
    float x4 = xp[4*H], x5 = xp[5*H], x6 = xp[6*H], x7 = xp[7*H];
    xp += 8 * H;                      // xp now points at row i+8

    #pragma unroll 1
    for (int i = 0; i < N - 8; i += 8) {
        SLOT(x0, 0, x0 = xp[0*H];)
        SLOT(x1, 1, x1 = xp[1*H];)
        SLOT(x2, 2, x2 = xp[2*H];)
        SLOT(x3, 3, x3 = xp[3*H];)
        SLOT(x4, 4, x4 = xp[4*H];)
        SLOT(x5, 5, x5 = xp[5*H];)
        SLOT(x6, 6, x6 = xp[6*H];)
        SLOT(x7, 7, x7 = xp[7*H];)
        xp += 8 * H;
        op += 8 * H;
    }
    // epilogue: last 8 rows, no prefetch
    SLOT(x0, 0, ) SLOT(x1, 1, ) SLOT(x2, 2, ) SLOT(x3, 3, )
    SLOT(x4, 4, ) SLOT(x5, 5, ) SLOT(x6, 6, ) SLOT(x7, 7, )
}

// ============================================================================
extern "C" void kernel_launch(void* const* d_in, const int* in_sizes, int n_in,
                              void* d_out, int out_size, void* d_ws, size_t ws_size,
                              hipStream_t stream) {
    const int*   y    = (const int*)  d_in[0];
    const float* emb  = (const float*)d_in[1];
    const float* W_ih = (const float*)d_in[2];
    const float* W_hh = (const float*)d_in[3];
    const float* b_ih = (const float*)d_in[4];
    const float* b_hh = (const float*)d_in[5];
    const float* h0   = (const float*)d_in[6];
    float* out = (float*)d_out;

    // Stage x' directly in d_out; scan overwrites it in place (strict
    // read-before-write per element within the single sequential wave).
    proj_kernel<<<dim3(N / 64), dim3(64), 0, stream>>>(y, emb, W_ih, b_ih, b_hh, out);
    scan_kernel<<<dim3(1), dim3(64), 0, stream>>>(W_hh, h0, out, out);
}